// Round 5
// baseline (210.694 us; speedup 1.0000x reference)
//
#include <hip/hip_runtime.h>

// fastmax attention. b=4,h=16,n=1024,d=64 fp32. bf16x3 split precision.
// v5 = v4 (named-reg prefetch, verified 80.1us) + three iter-chain cuts:
//  1) racc carry: QR rel-windows of consecutive jt overlap by 16 rows ->
//     racc[4] = prev iter's racc[0]; saves 6 MFMA + 4 ds_read_b128/iter.
//  2) Bst stride 18->17 words (odd): gather reads go 4-way-conflict (even
//     banks only) -> 2-way (free). [80][17] f32 = 5440 B fits 5760 overlay.
//  3) gather+split2+S-store fused, middle LDS fence dropped (per-wave
//     scratch W-after-R is safe: DS FIFO per wave + compiler may-alias).
// Structure: 64-row q-tiles, K/V/R staged in LDS, 2 blocks/CU, 3 barriers.

constexpr int N   = 1024;
constexpr int D   = 64;
constexpr int NBH = 64;
constexpr int LDT = 72;   // ushort stride of staged tiles

// ws layout (bytes)
constexpr size_t KH_OFF = 0;                                  // k_hi [bh][row][t]
constexpr size_t KL_OFF = KH_OFF + (size_t)NBH * N * D * 2;
constexpr size_t VH_OFF = KL_OFF + (size_t)NBH * N * D * 2;   // vt_hi [bh][dc][c]
constexpr size_t VL_OFF = VH_OFF + (size_t)NBH * N * D * 2;
constexpr size_t RH_OFF = VL_OFF + (size_t)NBH * N * D * 2;   // r_hi [rel 2048][t]
constexpr size_t RL_OFF = RH_OFF + (size_t)2048 * D * 2;

typedef short short8  __attribute__((ext_vector_type(8)));
typedef float float4v __attribute__((ext_vector_type(4)));

#define LDS_FENCE() asm volatile("s_waitcnt lgkmcnt(0)" ::: "memory")

__device__ __forceinline__ ushort f2bf(float x) {
    union { float f; unsigned u; } un; un.f = x;
    unsigned r = un.u + 0x7fffu + ((un.u >> 16) & 1u);   // RNE
    return (ushort)(r >> 16);
}
__device__ __forceinline__ float bf2f(ushort h) {
    union { unsigned u; float f; } un; un.u = ((unsigned)h) << 16;
    return un.f;
}
__device__ __forceinline__ void split2(float x, ushort& h, ushort& l) {
    h = f2bf(x);
    l = f2bf(x - bf2f(h));
}
__device__ __forceinline__ void pack16(const float* v, ushort* dh, ushort* dl) {
    ushort hh[16], ll[16];
#pragma unroll
    for (int j = 0; j < 16; ++j) split2(v[j], hh[j], ll[j]);
    uint4 a, b;
    a.x = hh[0] | (hh[1] << 16);  a.y = hh[2] | (hh[3] << 16);
    a.z = hh[4] | (hh[5] << 16);  a.w = hh[6] | (hh[7] << 16);
    b.x = hh[8] | (hh[9] << 16);  b.y = hh[10] | (hh[11] << 16);
    b.z = hh[12] | (hh[13] << 16); b.w = hh[14] | (hh[15] << 16);
    ((uint4*)dh)[0] = a; ((uint4*)dh)[1] = b;
    a.x = ll[0] | (ll[1] << 16);  a.y = ll[2] | (ll[3] << 16);
    a.z = ll[4] | (ll[5] << 16);  a.w = ll[6] | (ll[7] << 16);
    b.x = ll[8] | (ll[9] << 16);  b.y = ll[10] | (ll[11] << 16);
    b.z = ll[12] | (ll[13] << 16); b.w = ll[14] | (ll[15] << 16);
    ((uint4*)dl)[0] = a; ((uint4*)dl)[1] = b;
}

// ---- pre-kernels (unchanged) ----
__global__ __launch_bounds__(256) void prep_k(const float* __restrict__ kg,
                                              ushort* __restrict__ kh,
                                              ushort* __restrict__ kl) {
    const int bh = blockIdx.y;
    const int row = blockIdx.x * 64 + (threadIdx.x >> 2);
    const int seg = threadIdx.x & 3;
    const float4* p = (const float4*)(kg + ((size_t)bh * N + row) * D + seg * 16);
    float4 f[4] = {p[0], p[1], p[2], p[3]};
    float ss = 0.f;
#pragma unroll
    for (int i = 0; i < 4; ++i)
        ss += f[i].x * f[i].x + f[i].y * f[i].y + f[i].z * f[i].z + f[i].w * f[i].w;
    ss += __shfl_xor(ss, 1, 4);
    ss += __shfl_xor(ss, 2, 4);
    const float rn = rsqrtf(ss);
    float v[16];
#pragma unroll
    for (int i = 0; i < 4; ++i) {
        v[4 * i + 0] = f[i].x * rn; v[4 * i + 1] = f[i].y * rn;
        v[4 * i + 2] = f[i].z * rn; v[4 * i + 3] = f[i].w * rn;
    }
    const size_t o = ((size_t)bh * N + row) * D + seg * 16;
    pack16(v, kh + o, kl + o);
}

__global__ __launch_bounds__(256) void prep_rpe(const float* __restrict__ rg,
                                                ushort* __restrict__ rh,
                                                ushort* __restrict__ rl) {
    const int row = blockIdx.x * 64 + (threadIdx.x >> 2);
    if (row >= 2 * N - 1) return;
    const int seg = threadIdx.x & 3;
    const float4* p = (const float4*)(rg + (size_t)row * D + seg * 16);
    float4 f[4] = {p[0], p[1], p[2], p[3]};
    float v[16];
#pragma unroll
    for (int i = 0; i < 4; ++i) {
        v[4 * i + 0] = f[i].x; v[4 * i + 1] = f[i].y;
        v[4 * i + 2] = f[i].z; v[4 * i + 3] = f[i].w;
    }
    const size_t o = (size_t)row * D + seg * 16;
    pack16(v, rh + o, rl + o);
}

__global__ __launch_bounds__(256) void prep_v(const float* __restrict__ vg,
                                              const float* __restrict__ ng,
                                              ushort* __restrict__ vh,
                                              ushort* __restrict__ vl) {
    __shared__ ushort Th[64 * 72], Tl[64 * 72];
    const int bh = blockIdx.y, c0 = blockIdx.x * 64;
    const int cl = threadIdx.x >> 2, seg = threadIdx.x & 3;
    {
        const float4* pv = (const float4*)(vg + ((size_t)bh * N + c0 + cl) * D + seg * 16);
        const float4* pn = (const float4*)(ng + ((size_t)bh * N + c0 + cl) * D + seg * 16);
#pragma unroll
        for (int i = 0; i < 4; ++i) {
            float4 fv = pv[i], fn = pn[i];
            float va[4] = {fv.x + 0.1f * fn.x, fv.y + 0.1f * fn.y,
                           fv.z + 0.1f * fn.z, fv.w + 0.1f * fn.w};
#pragma unroll
            for (int j = 0; j < 4; ++j) {
                ushort hh, ll;
                split2(va[j], hh, ll);
                const int dc = seg * 16 + i * 4 + j;
                Th[dc * 72 + cl] = hh;
                Tl[dc * 72 + cl] = ll;
            }
        }
    }
    __syncthreads();
    {
        const int dc = threadIdx.x >> 2;
        const size_t o = ((size_t)bh * D + dc) * N + c0 + seg * 16;
        uint4* sh = (uint4*)&Th[dc * 72 + seg * 16];
        uint4* sl = (uint4*)&Tl[dc * 72 + seg * 16];
        ((uint4*)(vh + o))[0] = sh[0]; ((uint4*)(vh + o))[1] = sh[1];
        ((uint4*)(vl + o))[0] = sl[0]; ((uint4*)(vl + o))[1] = sl[1];
    }
}

// ---- main ----
__device__ __forceinline__ float4v mfma6(short8 ah0, short8 ah1, short8 al0, short8 al1,
                                         const ushort* ph, const ushort* pl, float4v c) {
    short8 bh0 = *(const short8*)ph;
    short8 bh1 = *(const short8*)(ph + 32);
    short8 bl0 = *(const short8*)pl;
    short8 bl1 = *(const short8*)(pl + 32);
    c = __builtin_amdgcn_mfma_f32_16x16x32_bf16(ah0, bh0, c, 0, 0, 0);
    c = __builtin_amdgcn_mfma_f32_16x16x32_bf16(ah1, bh1, c, 0, 0, 0);
    c = __builtin_amdgcn_mfma_f32_16x16x32_bf16(ah0, bl0, c, 0, 0, 0);
    c = __builtin_amdgcn_mfma_f32_16x16x32_bf16(ah1, bl1, c, 0, 0, 0);
    c = __builtin_amdgcn_mfma_f32_16x16x32_bf16(al0, bh0, c, 0, 0, 0);
    c = __builtin_amdgcn_mfma_f32_16x16x32_bf16(al1, bh1, c, 0, 0, 0);
    return c;
}

// Prefetch next K/V/R tile into 16 NAMED uint4 (64 VGPRs). No arrays, no
// lambdas -> nothing address-taken -> guaranteed register allocation.
#define PREFETCH(i0loc, jtv) do {                                         \
    const int j0_   = (jtv) * 64;                                         \
    const int rel0_ = (i0loc) - j0_ + N - 64;                             \
    const ushort* gKh_ = khb + (size_t)j0_ * D;                           \
    const ushort* gKl_ = klb + (size_t)j0_ * D;                           \
    const ushort* gVh_ = vhb + j0_;                                       \
    const ushort* gVl_ = vlb + j0_;                                       \
    const ushort* gRh_ = rh + (size_t)rel0_ * D;                          \
    const ushort* gRl_ = rl + (size_t)rel0_ * D;                          \
    pKh0 = *(const uint4*)&gKh_[r0 * D + c8];                             \
    pKh1 = *(const uint4*)&gKh_[(r0 + 32) * D + c8];                      \
    pKl0 = *(const uint4*)&gKl_[r0 * D + c8];                             \
    pKl1 = *(const uint4*)&gKl_[(r0 + 32) * D + c8];                      \
    pVh0 = *(const uint4*)&gVh_[(size_t)r0 * N + c8];                     \
    pVh1 = *(const uint4*)&gVh_[(size_t)(r0 + 32) * N + c8];              \
    pVl0 = *(const uint4*)&gVl_[(size_t)r0 * N + c8];                     \
    pVl1 = *(const uint4*)&gVl_[(size_t)(r0 + 32) * N + c8];              \
    pRh0 = *(const uint4*)&gRh_[r0 * D + c8];                             \
    pRh1 = *(const uint4*)&gRh_[(r0 + 32) * D + c8];                      \
    pRh2 = *(const uint4*)&gRh_[(r0 + 64) * D + c8];                      \
    pRh3 = *(const uint4*)&gRh_[(r0 + 96) * D + c8];                      \
    pRl0 = *(const uint4*)&gRl_[r0 * D + c8];                             \
    pRl1 = *(const uint4*)&gRl_[(r0 + 32) * D + c8];                      \
    pRl2 = *(const uint4*)&gRl_[(r0 + 64) * D + c8];                      \
    pRl3 = *(const uint4*)&gRl_[(r0 + 96) * D + c8];                      \
} while (0)

#define STAGE_WRITE() do {                                                \
    *(uint4*)&Kh[r0 * LDT + c8]        = pKh0;                            \
    *(uint4*)&Kh[(r0 + 32) * LDT + c8] = pKh1;                            \
    *(uint4*)&Kl[r0 * LDT + c8]        = pKl0;                            \
    *(uint4*)&Kl[(r0 + 32) * LDT + c8] = pKl1;                            \
    *(uint4*)&Vh[r0 * LDT + c8]        = pVh0;                            \
    *(uint4*)&Vh[(r0 + 32) * LDT + c8] = pVh1;                            \
    *(uint4*)&Vl[r0 * LDT + c8]        = pVl0;                            \
    *(uint4*)&Vl[(r0 + 32) * LDT + c8] = pVl1;                            \
    *(uint4*)&Rh[r0 * LDT + c8]        = pRh0;                            \
    *(uint4*)&Rh[(r0 + 32) * LDT + c8] = pRh1;                            \
    *(uint4*)&Rh[(r0 + 64) * LDT + c8] = pRh2;                            \
    *(uint4*)&Rh[(r0 + 96) * LDT + c8] = pRh3;                            \
    *(uint4*)&Rl[r0 * LDT + c8]        = pRl0;                            \
    *(uint4*)&Rl[(r0 + 32) * LDT + c8] = pRl1;                            \
    *(uint4*)&Rl[(r0 + 64) * LDT + c8] = pRl2;                            \
    *(uint4*)&Rl[(r0 + 96) * LDT + c8] = pRl3;                            \
} while (0)

__global__ __launch_bounds__(256, 2)
void fastmax_main(const float* __restrict__ qg,
                  const ushort* __restrict__ kh, const ushort* __restrict__ kl,
                  const ushort* __restrict__ vh, const ushort* __restrict__ vl,
                  const ushort* __restrict__ rh, const ushort* __restrict__ rl,
                  float* __restrict__ og) {
    __shared__ __align__(16) char smem[73728];
    ushort* Kh = (ushort*)smem;           // [64][LDT]
    ushort* Kl = Kh + 64 * LDT;
    ushort* Rh = Kl + 64 * LDT;           // [128][LDT]
    ushort* Rl = Rh + 128 * LDT;
    ushort* Vh = Rl + 128 * LDT;          // [64][LDT] (dc-major)
    ushort* Vl = Vh + 64 * LDT;

    const int tid  = threadIdx.x;
    const int lane = tid & 63;
    const int wv   = tid >> 6;
    const int bh   = blockIdx.y;
    const int x    = lane & 15;
    const int quad = lane >> 4;
    const int band = wv * 16;
    const int r0   = tid >> 3;            // staging row for this thread
    const int c8   = (tid & 7) * 8;       // staging col (ushorts)

    // per-wave scratch overlays Kh/Kl/start-of-Rh (dead between barriers B..D)
    float*  Bst = (float*)(smem + wv * 5760);   // [80][17] f32 (odd word stride)
    ushort* Sh  = (ushort*)(smem + wv * 5760);  // [16][LDT] bf16
    ushort* Sl  = Sh + 16 * LDT;

    const ushort* khb = kh + (size_t)bh * N * D;
    const ushort* klb = kl + (size_t)bh * N * D;
    const ushort* vhb = vh + (size_t)bh * D * N;
    const ushort* vlb = vl + (size_t)bh * D * N;

    // named prefetch registers (16 uint4 = 64 VGPRs)
    uint4 pKh0, pKh1, pKl0, pKl1, pVh0, pVh1, pVl0, pVl1;
    uint4 pRh0, pRh1, pRh2, pRh3, pRl0, pRl1, pRl2, pRl3;

    for (int half = 0; half < 2; ++half) {
        const int bix = half == 0 ? (int)blockIdx.x + 8 : 7 - (int)blockIdx.x;
        const int i0  = bix * 64;

        // ---- this wave's 16 q rows -> normalized bf16x2 A-frags ----
        const float* qrow = qg + ((size_t)bh * N + i0 + band + x) * D;
        float qf[16];
        *(float4*)&qf[0]  = *(const float4*)(qrow + quad * 8);
        *(float4*)&qf[4]  = *(const float4*)(qrow + quad * 8 + 4);
        *(float4*)&qf[8]  = *(const float4*)(qrow + 32 + quad * 8);
        *(float4*)&qf[12] = *(const float4*)(qrow + 32 + quad * 8 + 4);
        float ss = 0.f;
#pragma unroll
        for (int j = 0; j < 16; ++j) ss += qf[j] * qf[j];
        ss += __shfl_xor(ss, 16);
        ss += __shfl_xor(ss, 32);
        const float rn = rsqrtf(ss);
        short8 qh0, ql0, qh1, ql1;
#pragma unroll
        for (int j = 0; j < 8; ++j) {
            ushort h, l;
            split2(qf[j] * rn, h, l);      qh0[j] = (short)h; ql0[j] = (short)l;
            split2(qf[8 + j] * rn, h, l);  qh1[j] = (short)h; ql1[j] = (short)l;
        }

        float4v oacc[4];
#pragma unroll
        for (int i = 0; i < 4; ++i) oacc[i] = (float4v){0.f, 0.f, 0.f, 0.f};
        float pden[4] = {0.f, 0.f, 0.f, 0.f};
        float4v racc_carry = (float4v){0.f, 0.f, 0.f, 0.f};

        if (half == 0) PREFETCH(i0, 0);   // cold start; all later tiles overlap

        for (int jt = 0; jt <= bix; ++jt) {
            // ---- dump prefetched tile to LDS (prev iter's reads done at D) ----
            STAGE_WRITE();
            __syncthreads();   // A: staging visible

            // ---- issue next prefetch (drains under QK/QR/PV MFMAs) ----
            if (jt < bix) {
                PREFETCH(i0, jt + 1);
            } else if (half == 0) {
                const int i0n = (7 - (int)blockIdx.x) * 64;
                PREFETCH(i0n, 0);
            }

            // ---- QK^T ----
            __builtin_amdgcn_s_setprio(1);
            float4v sacc[4];
#pragma unroll
            for (int nt = 0; nt < 4; ++nt) {
                const int off = (nt * 16 + x) * LDT + quad * 8;
                float4v c = (float4v){0.f, 0.f, 0.f, 0.f};
                sacc[nt] = mfma6(qh0, qh1, ql0, ql1, &Kh[off], &Kl[off], c);
            }
            // ---- QR: w-tiles 0..3 computed; tile 4 carried from prev iter's
            //      tile 0 (rel windows of consecutive jt overlap by 16 rows).
            float4v racc[5];
#pragma unroll
            for (int t = 0; t < 4; ++t) {
                const int off = (band + t * 16 + x) * LDT + quad * 8;
                float4v c = (float4v){0.f, 0.f, 0.f, 0.f};
                racc[t] = mfma6(qh0, qh1, ql0, ql1, &Rh[off], &Rl[off], c);
            }
            if (jt == 0) {
                const int off = (band + 64 + x) * LDT + quad * 8;
                float4v c = (float4v){0.f, 0.f, 0.f, 0.f};
                racc[4] = mfma6(qh0, qh1, ql0, ql1, &Rh[off], &Rl[off], c);
            } else {
                racc[4] = racc_carry;
            }
            racc_carry = racc[0];
            __builtin_amdgcn_s_setprio(0);
            __syncthreads();   // B: K/R LDS reads done; scratch region free

            // ---- intra-wave Bst transpose (stride 17 words: conflict-free) ----
#pragma unroll
            for (int t = 0; t < 5; ++t) {
                float* p = &Bst[(t * 16 + x) * 17 + quad * 4];
                float2 a; a.x = racc[t][0]; a.y = racc[t][1];
                float2 b; b.x = racc[t][2]; b.y = racc[t][3];
                *(float2*)p = a;
                *(float2*)(p + 2) = b;
            }
            LDS_FENCE();

            // ---- fused gather + split + S hi/lo store (read latency hides
            //      under split2 VALU; DS FIFO keeps W-after-R safe) ----
            const bool diag = (jt == bix);
#pragma unroll
            for (int nt = 0; nt < 4; ++nt) {
#pragma unroll
                for (int rr = 0; rr < 4; ++rr) {
                    const int rt = band + quad * 4 + rr;
                    const int ct = nt * 16 + x;
                    const int wl = rt - ct + 63 - band;     // [0, 78]
                    float val = sacc[nt][rr] + Bst[wl * 17 + quad * 4 + rr] + 1.0f;
                    if (diag && ct > rt) val = 0.f;
                    pden[rr] += val;
                    ushort hh, ll;
                    split2(val, hh, ll);
                    Sh[(quad * 4 + rr) * LDT + nt * 16 + x] = hh;
                    Sl[(quad * 4 + rr) * LDT + nt * 16 + x] = ll;
                }
            }
            LDS_FENCE();
            const short8 sh0 = *(const short8*)&Sh[x * LDT + quad * 8];
            const short8 sh1 = *(const short8*)&Sh[x * LDT + 32 + quad * 8];
            const short8 sl0 = *(const short8*)&Sl[x * LDT + quad * 8];
            const short8 sl1 = *(const short8*)&Sl[x * LDT + 32 + quad * 8];

            // ---- O += S @ V' ----
            __builtin_amdgcn_s_setprio(1);
#pragma unroll
            for (int nt = 0; nt < 4; ++nt) {
                const int off = (nt * 16 + x) * LDT + quad * 8;
                oacc[nt] = mfma6(sh0, sh1, sl0, sl1, &Vh[off], &Vl[off], oacc[nt]);
            }
            __builtin_amdgcn_s_setprio(0);
            __syncthreads();   // D: all reads done; next iter may restage
        }

        // ---- denominators + store ----
        float inv[4];
#pragma unroll
        for (int rr = 0; rr < 4; ++rr) {
            float d = pden[rr];
            d += __shfl_xor(d, 1, 16);
            d += __shfl_xor(d, 2, 16);
            d += __shfl_xor(d, 4, 16);
            d += __shfl_xor(d, 8, 16);
            inv[rr] = 1.0f / d;
        }
        float* outp = og + ((size_t)bh * N + i0 + band) * D;
#pragma unroll
        for (int nt = 0; nt < 4; ++nt)
#pragma unroll
            for (int rr = 0; rr < 4; ++rr)
                outp[(size_t)(quad * 4 + rr) * D + nt * 16 + x] = oacc[nt][rr] * inv[rr];
    }
}

extern "C" void kernel_launch(void* const* d_in, const int* in_sizes, int n_in,
                              void* d_out, int out_size, void* d_ws, size_t ws_size,
                              hipStream_t stream) {
    const float* q   = (const float*)d_in[0];
    const float* k   = (const float*)d_in[1];
    const float* v   = (const float*)d_in[2];
    const float* dn  = (const float*)d_in[3];
    const float* rpe = (const float*)d_in[4];
    float* out = (float*)d_out;
    char* ws = (char*)d_ws;

    ushort* kh = (ushort*)(ws + KH_OFF);
    ushort* kl = (ushort*)(ws + KL_OFF);
    ushort* vh = (ushort*)(ws + VH_OFF);
    ushort* vl = (ushort*)(ws + VL_OFF);
    ushort* rh = (ushort*)(ws + RH_OFF);
    ushort* rl = (ushort*)(ws + RL_OFF);

    prep_k  <<<dim3(N / 64, NBH), 256, 0, stream>>>(k, kh, kl);
    prep_v  <<<dim3(N / 64, NBH), 256, 0, stream>>>(v, dn, vh, vl);
    prep_rpe<<<dim3(32), 256, 0, stream>>>(rpe, rh, rl);
    fastmax_main<<<dim3(8, NBH), 256, 0, stream>>>(q, kh, kl, vh, vl, rh, rl, out);
}

// Round 6
// 210.369 us; speedup vs baseline: 1.0015x; 1.0015x over previous
//
#include <hip/hip_runtime.h>

// fastmax attention. b=4,h=16,n=1024,d=64 fp32. bf16x3 split precision.
// v6 = v4 (named-reg prefetch, verified 80.1us) + racc carry + Bst stride 17.
// v5's regression isolated to the dropped mid-fence (may-alias forced
// per-element LDS serialization, +1900cy/iter); v6 restores v4's batched
// gather -> FENCE -> split/store phases.
//  - racc carry: QR rel-windows of consecutive jt overlap by 16 rows ->
//    racc[4] = prev iter's racc[0]; saves 6 MFMA + 4 ds_read_b128/iter.
//  - Bst stride 18->17 f32 words (odd): gather reads 4-way -> 2-way banks.
// Structure: 64-row q-tiles, K/V/R staged in LDS, 2 blocks/CU, 3 barriers.

constexpr int N   = 1024;
constexpr int D   = 64;
constexpr int NBH = 64;
constexpr int LDT = 72;   // ushort stride of staged tiles

// ws layout (bytes)
constexpr size_t KH_OFF = 0;                                  // k_hi [bh][row][t]
constexpr size_t KL_OFF = KH_OFF + (size_t)NBH * N * D * 2;
constexpr size_t VH_OFF = KL_OFF + (size_t)NBH * N * D * 2;   // vt_hi [bh][dc][c]
constexpr size_t VL_OFF = VH_OFF + (size_t)NBH * N * D * 2;
constexpr size_t RH_OFF = VL_OFF + (size_t)NBH * N * D * 2;   // r_hi [rel 2048][t]
constexpr size_t RL_OFF = RH_OFF + (size_t)2048 * D * 2;

typedef short short8  __attribute__((ext_vector_type(8)));
typedef float float4v __attribute__((ext_vector_type(4)));

#define LDS_FENCE() asm volatile("s_waitcnt lgkmcnt(0)" ::: "memory")

__device__ __forceinline__ ushort f2bf(float x) {
    union { float f; unsigned u; } un; un.f = x;
    unsigned r = un.u + 0x7fffu + ((un.u >> 16) & 1u);   // RNE
    return (ushort)(r >> 16);
}
__device__ __forceinline__ float bf2f(ushort h) {
    union { unsigned u; float f; } un; un.u = ((unsigned)h) << 16;
    return un.f;
}
__device__ __forceinline__ void split2(float x, ushort& h, ushort& l) {
    h = f2bf(x);
    l = f2bf(x - bf2f(h));
}
__device__ __forceinline__ void pack16(const float* v, ushort* dh, ushort* dl) {
    ushort hh[16], ll[16];
#pragma unroll
    for (int j = 0; j < 16; ++j) split2(v[j], hh[j], ll[j]);
    uint4 a, b;
    a.x = hh[0] | (hh[1] << 16);  a.y = hh[2] | (hh[3] << 16);
    a.z = hh[4] | (hh[5] << 16);  a.w = hh[6] | (hh[7] << 16);
    b.x = hh[8] | (hh[9] << 16);  b.y = hh[10] | (hh[11] << 16);
    b.z = hh[12] | (hh[13] << 16); b.w = hh[14] | (hh[15] << 16);
    ((uint4*)dh)[0] = a; ((uint4*)dh)[1] = b;
    a.x = ll[0] | (ll[1] << 16);  a.y = ll[2] | (ll[3] << 16);
    a.z = ll[4] | (ll[5] << 16);  a.w = ll[6] | (ll[7] << 16);
    b.x = ll[8] | (ll[9] << 16);  b.y = ll[10] | (ll[11] << 16);
    b.z = ll[12] | (ll[13] << 16); b.w = ll[14] | (ll[15] << 16);
    ((uint4*)dl)[0] = a; ((uint4*)dl)[1] = b;
}

// ---- pre-kernels (unchanged) ----
__global__ __launch_bounds__(256) void prep_k(const float* __restrict__ kg,
                                              ushort* __restrict__ kh,
                                              ushort* __restrict__ kl) {
    const int bh = blockIdx.y;
    const int row = blockIdx.x * 64 + (threadIdx.x >> 2);
    const int seg = threadIdx.x & 3;
    const float4* p = (const float4*)(kg + ((size_t)bh * N + row) * D + seg * 16);
    float4 f[4] = {p[0], p[1], p[2], p[3]};
    float ss = 0.f;
#pragma unroll
    for (int i = 0; i < 4; ++i)
        ss += f[i].x * f[i].x + f[i].y * f[i].y + f[i].z * f[i].z + f[i].w * f[i].w;
    ss += __shfl_xor(ss, 1, 4);
    ss += __shfl_xor(ss, 2, 4);
    const float rn = rsqrtf(ss);
    float v[16];
#pragma unroll
    for (int i = 0; i < 4; ++i) {
        v[4 * i + 0] = f[i].x * rn; v[4 * i + 1] = f[i].y * rn;
        v[4 * i + 2] = f[i].z * rn; v[4 * i + 3] = f[i].w * rn;
    }
    const size_t o = ((size_t)bh * N + row) * D + seg * 16;
    pack16(v, kh + o, kl + o);
}

__global__ __launch_bounds__(256) void prep_rpe(const float* __restrict__ rg,
                                                ushort* __restrict__ rh,
                                                ushort* __restrict__ rl) {
    const int row = blockIdx.x * 64 + (threadIdx.x >> 2);
    if (row >= 2 * N - 1) return;
    const int seg = threadIdx.x & 3;
    const float4* p = (const float4*)(rg + (size_t)row * D + seg * 16);
    float4 f[4] = {p[0], p[1], p[2], p[3]};
    float v[16];
#pragma unroll
    for (int i = 0; i < 4; ++i) {
        v[4 * i + 0] = f[i].x; v[4 * i + 1] = f[i].y;
        v[4 * i + 2] = f[i].z; v[4 * i + 3] = f[i].w;
    }
    const size_t o = (size_t)row * D + seg * 16;
    pack16(v, rh + o, rl + o);
}

__global__ __launch_bounds__(256) void prep_v(const float* __restrict__ vg,
                                              const float* __restrict__ ng,
                                              ushort* __restrict__ vh,
                                              ushort* __restrict__ vl) {
    __shared__ ushort Th[64 * 72], Tl[64 * 72];
    const int bh = blockIdx.y, c0 = blockIdx.x * 64;
    const int cl = threadIdx.x >> 2, seg = threadIdx.x & 3;
    {
        const float4* pv = (const float4*)(vg + ((size_t)bh * N + c0 + cl) * D + seg * 16);
        const float4* pn = (const float4*)(ng + ((size_t)bh * N + c0 + cl) * D + seg * 16);
#pragma unroll
        for (int i = 0; i < 4; ++i) {
            float4 fv = pv[i], fn = pn[i];
            float va[4] = {fv.x + 0.1f * fn.x, fv.y + 0.1f * fn.y,
                           fv.z + 0.1f * fn.z, fv.w + 0.1f * fn.w};
#pragma unroll
            for (int j = 0; j < 4; ++j) {
                ushort hh, ll;
                split2(va[j], hh, ll);
                const int dc = seg * 16 + i * 4 + j;
                Th[dc * 72 + cl] = hh;
                Tl[dc * 72 + cl] = ll;
            }
        }
    }
    __syncthreads();
    {
        const int dc = threadIdx.x >> 2;
        const size_t o = ((size_t)bh * D + dc) * N + c0 + seg * 16;
        uint4* sh = (uint4*)&Th[dc * 72 + seg * 16];
        uint4* sl = (uint4*)&Tl[dc * 72 + seg * 16];
        ((uint4*)(vh + o))[0] = sh[0]; ((uint4*)(vh + o))[1] = sh[1];
        ((uint4*)(vl + o))[0] = sl[0]; ((uint4*)(vl + o))[1] = sl[1];
    }
}

// ---- main ----
__device__ __forceinline__ float4v mfma6(short8 ah0, short8 ah1, short8 al0, short8 al1,
                                         const ushort* ph, const ushort* pl, float4v c) {
    short8 bh0 = *(const short8*)ph;
    short8 bh1 = *(const short8*)(ph + 32);
    short8 bl0 = *(const short8*)pl;
    short8 bl1 = *(const short8*)(pl + 32);
    c = __builtin_amdgcn_mfma_f32_16x16x32_bf16(ah0, bh0, c, 0, 0, 0);
    c = __builtin_amdgcn_mfma_f32_16x16x32_bf16(ah1, bh1, c, 0, 0, 0);
    c = __builtin_amdgcn_mfma_f32_16x16x32_bf16(ah0, bl0, c, 0, 0, 0);
    c = __builtin_amdgcn_mfma_f32_16x16x32_bf16(ah1, bl1, c, 0, 0, 0);
    c = __builtin_amdgcn_mfma_f32_16x16x32_bf16(al0, bh0, c, 0, 0, 0);
    c = __builtin_amdgcn_mfma_f32_16x16x32_bf16(al1, bh1, c, 0, 0, 0);
    return c;
}

// Prefetch next K/V/R tile into 16 NAMED uint4 (64 VGPRs). No arrays, no
// lambdas -> nothing address-taken -> guaranteed register allocation.
#define PREFETCH(i0loc, jtv) do {                                         \
    const int j0_   = (jtv) * 64;                                         \
    const int rel0_ = (i0loc) - j0_ + N - 64;                             \
    const ushort* gKh_ = khb + (size_t)j0_ * D;                           \
    const ushort* gKl_ = klb + (size_t)j0_ * D;                           \
    const ushort* gVh_ = vhb + j0_;                                       \
    const ushort* gVl_ = vlb + j0_;                                       \
    const ushort* gRh_ = rh + (size_t)rel0_ * D;                          \
    const ushort* gRl_ = rl + (size_t)rel0_ * D;                          \
    pKh0 = *(const uint4*)&gKh_[r0 * D + c8];                             \
    pKh1 = *(const uint4*)&gKh_[(r0 + 32) * D + c8];                      \
    pKl0 = *(const uint4*)&gKl_[r0 * D + c8];                             \
    pKl1 = *(const uint4*)&gKl_[(r0 + 32) * D + c8];                      \
    pVh0 = *(const uint4*)&gVh_[(size_t)r0 * N + c8];                     \
    pVh1 = *(const uint4*)&gVh_[(size_t)(r0 + 32) * N + c8];              \
    pVl0 = *(const uint4*)&gVl_[(size_t)r0 * N + c8];                     \
    pVl1 = *(const uint4*)&gVl_[(size_t)(r0 + 32) * N + c8];              \
    pRh0 = *(const uint4*)&gRh_[r0 * D + c8];                             \
    pRh1 = *(const uint4*)&gRh_[(r0 + 32) * D + c8];                      \
    pRh2 = *(const uint4*)&gRh_[(r0 + 64) * D + c8];                      \
    pRh3 = *(const uint4*)&gRh_[(r0 + 96) * D + c8];                      \
    pRl0 = *(const uint4*)&gRl_[r0 * D + c8];                             \
    pRl1 = *(const uint4*)&gRl_[(r0 + 32) * D + c8];                      \
    pRl2 = *(const uint4*)&gRl_[(r0 + 64) * D + c8];                      \
    pRl3 = *(const uint4*)&gRl_[(r0 + 96) * D + c8];                      \
} while (0)

#define STAGE_WRITE() do {                                                \
    *(uint4*)&Kh[r0 * LDT + c8]        = pKh0;                            \
    *(uint4*)&Kh[(r0 + 32) * LDT + c8] = pKh1;                            \
    *(uint4*)&Kl[r0 * LDT + c8]        = pKl0;                            \
    *(uint4*)&Kl[(r0 + 32) * LDT + c8] = pKl1;                            \
    *(uint4*)&Vh[r0 * LDT + c8]        = pVh0;                            \
    *(uint4*)&Vh[(r0 + 32) * LDT + c8] = pVh1;                            \
    *(uint4*)&Vl[r0 * LDT + c8]        = pVl0;                            \
    *(uint4*)&Vl[(r0 + 32) * LDT + c8] = pVl1;                            \
    *(uint4*)&Rh[r0 * LDT + c8]        = pRh0;                            \
    *(uint4*)&Rh[(r0 + 32) * LDT + c8] = pRh1;                            \
    *(uint4*)&Rh[(r0 + 64) * LDT + c8] = pRh2;                            \
    *(uint4*)&Rh[(r0 + 96) * LDT + c8] = pRh3;                            \
    *(uint4*)&Rl[r0 * LDT + c8]        = pRl0;                            \
    *(uint4*)&Rl[(r0 + 32) * LDT + c8] = pRl1;                            \
    *(uint4*)&Rl[(r0 + 64) * LDT + c8] = pRl2;                            \
    *(uint4*)&Rl[(r0 + 96) * LDT + c8] = pRl3;                            \
} while (0)

__global__ __launch_bounds__(256, 2)
void fastmax_main(const float* __restrict__ qg,
                  const ushort* __restrict__ kh, const ushort* __restrict__ kl,
                  const ushort* __restrict__ vh, const ushort* __restrict__ vl,
                  const ushort* __restrict__ rh, const ushort* __restrict__ rl,
                  float* __restrict__ og) {
    __shared__ __align__(16) char smem[73728];
    ushort* Kh = (ushort*)smem;           // [64][LDT]
    ushort* Kl = Kh + 64 * LDT;
    ushort* Rh = Kl + 64 * LDT;           // [128][LDT]
    ushort* Rl = Rh + 128 * LDT;
    ushort* Vh = Rl + 128 * LDT;          // [64][LDT] (dc-major)
    ushort* Vl = Vh + 64 * LDT;

    const int tid  = threadIdx.x;
    const int lane = tid & 63;
    const int wv   = tid >> 6;
    const int bh   = blockIdx.y;
    const int x    = lane & 15;
    const int quad = lane >> 4;
    const int band = wv * 16;
    const int r0   = tid >> 3;            // staging row for this thread
    const int c8   = (tid & 7) * 8;       // staging col (ushorts)

    // per-wave scratch overlays Kh/Kl/start-of-Rh (dead between barriers B..D)
    float*  Bst = (float*)(smem + wv * 5760);   // [80][17] f32 (odd word stride)
    ushort* Sh  = (ushort*)(smem + wv * 5760);  // [16][LDT] bf16
    ushort* Sl  = Sh + 16 * LDT;

    const ushort* khb = kh + (size_t)bh * N * D;
    const ushort* klb = kl + (size_t)bh * N * D;
    const ushort* vhb = vh + (size_t)bh * D * N;
    const ushort* vlb = vl + (size_t)bh * D * N;

    // named prefetch registers (16 uint4 = 64 VGPRs)
    uint4 pKh0, pKh1, pKl0, pKl1, pVh0, pVh1, pVl0, pVl1;
    uint4 pRh0, pRh1, pRh2, pRh3, pRl0, pRl1, pRl2, pRl3;

    for (int half = 0; half < 2; ++half) {
        const int bix = half == 0 ? (int)blockIdx.x + 8 : 7 - (int)blockIdx.x;
        const int i0  = bix * 64;

        // ---- this wave's 16 q rows -> normalized bf16x2 A-frags ----
        const float* qrow = qg + ((size_t)bh * N + i0 + band + x) * D;
        float qf[16];
        *(float4*)&qf[0]  = *(const float4*)(qrow + quad * 8);
        *(float4*)&qf[4]  = *(const float4*)(qrow + quad * 8 + 4);
        *(float4*)&qf[8]  = *(const float4*)(qrow + 32 + quad * 8);
        *(float4*)&qf[12] = *(const float4*)(qrow + 32 + quad * 8 + 4);
        float ss = 0.f;
#pragma unroll
        for (int j = 0; j < 16; ++j) ss += qf[j] * qf[j];
        ss += __shfl_xor(ss, 16);
        ss += __shfl_xor(ss, 32);
        const float rn = rsqrtf(ss);
        short8 qh0, ql0, qh1, ql1;
#pragma unroll
        for (int j = 0; j < 8; ++j) {
            ushort h, l;
            split2(qf[j] * rn, h, l);      qh0[j] = (short)h; ql0[j] = (short)l;
            split2(qf[8 + j] * rn, h, l);  qh1[j] = (short)h; ql1[j] = (short)l;
        }

        float4v oacc[4];
#pragma unroll
        for (int i = 0; i < 4; ++i) oacc[i] = (float4v){0.f, 0.f, 0.f, 0.f};
        float pden[4] = {0.f, 0.f, 0.f, 0.f};
        float4v racc_carry = (float4v){0.f, 0.f, 0.f, 0.f};

        if (half == 0) PREFETCH(i0, 0);   // cold start; all later tiles overlap

        for (int jt = 0; jt <= bix; ++jt) {
            // ---- dump prefetched tile to LDS (prev iter's reads done at D) ----
            STAGE_WRITE();
            __syncthreads();   // A: staging visible

            // ---- issue next prefetch (drains under QK/QR/PV MFMAs) ----
            if (jt < bix) {
                PREFETCH(i0, jt + 1);
            } else if (half == 0) {
                const int i0n = (7 - (int)blockIdx.x) * 64;
                PREFETCH(i0n, 0);
            }

            // ---- QK^T ----
            __builtin_amdgcn_s_setprio(1);
            float4v sacc[4];
#pragma unroll
            for (int nt = 0; nt < 4; ++nt) {
                const int off = (nt * 16 + x) * LDT + quad * 8;
                float4v c = (float4v){0.f, 0.f, 0.f, 0.f};
                sacc[nt] = mfma6(qh0, qh1, ql0, ql1, &Kh[off], &Kl[off], c);
            }
            // ---- QR: w-tiles 0..3 computed; tile 4 carried from prev iter's
            //      tile 0 (rel windows of consecutive jt overlap by 16 rows).
            float4v racc[5];
#pragma unroll
            for (int t = 0; t < 4; ++t) {
                const int off = (band + t * 16 + x) * LDT + quad * 8;
                float4v c = (float4v){0.f, 0.f, 0.f, 0.f};
                racc[t] = mfma6(qh0, qh1, ql0, ql1, &Rh[off], &Rl[off], c);
            }
            if (jt == 0) {
                const int off = (band + 64 + x) * LDT + quad * 8;
                float4v c = (float4v){0.f, 0.f, 0.f, 0.f};
                racc[4] = mfma6(qh0, qh1, ql0, ql1, &Rh[off], &Rl[off], c);
            } else {
                racc[4] = racc_carry;
            }
            racc_carry = racc[0];
            __builtin_amdgcn_s_setprio(0);
            __syncthreads();   // B: K/R LDS reads done; scratch region free

            // ---- intra-wave Bst transpose (stride 17 words) ----
#pragma unroll
            for (int t = 0; t < 5; ++t) {
                float* p = &Bst[(t * 16 + x) * 17 + quad * 4];
                float2 a; a.x = racc[t][0]; a.y = racc[t][1];
                float2 b; b.x = racc[t][2]; b.y = racc[t][3];
                *(float2*)p = a;
                *(float2*)(p + 2) = b;
            }
            LDS_FENCE();

            // ---- gather bias, assemble S, denom (batched reads) ----
            const bool diag = (jt == bix);
            float s[4][4];
#pragma unroll
            for (int nt = 0; nt < 4; ++nt) {
#pragma unroll
                for (int rr = 0; rr < 4; ++rr) {
                    const int rt = band + quad * 4 + rr;
                    const int ct = nt * 16 + x;
                    const int wl = rt - ct + 63 - band;     // [0, 78]
                    float val = sacc[nt][rr] + Bst[wl * 17 + quad * 4 + rr] + 1.0f;
                    if (diag && ct > rt) val = 0.f;
                    pden[rr] += val;
                    s[nt][rr] = val;
                }
            }
            LDS_FENCE();

            // ---- intra-wave S hi/lo store + A-frag reload ----
#pragma unroll
            for (int nt = 0; nt < 4; ++nt)
#pragma unroll
                for (int rr = 0; rr < 4; ++rr) {
                    ushort hh, ll;
                    split2(s[nt][rr], hh, ll);
                    Sh[(quad * 4 + rr) * LDT + nt * 16 + x] = hh;
                    Sl[(quad * 4 + rr) * LDT + nt * 16 + x] = ll;
                }
            LDS_FENCE();
            const short8 sh0 = *(const short8*)&Sh[x * LDT + quad * 8];
            const short8 sh1 = *(const short8*)&Sh[x * LDT + 32 + quad * 8];
            const short8 sl0 = *(const short8*)&Sl[x * LDT + quad * 8];
            const short8 sl1 = *(const short8*)&Sl[x * LDT + 32 + quad * 8];

            // ---- O += S @ V' ----
            __builtin_amdgcn_s_setprio(1);
#pragma unroll
            for (int nt = 0; nt < 4; ++nt) {
                const int off = (nt * 16 + x) * LDT + quad * 8;
                oacc[nt] = mfma6(sh0, sh1, sl0, sl1, &Vh[off], &Vl[off], oacc[nt]);
            }
            __builtin_amdgcn_s_setprio(0);
            __syncthreads();   // D: all reads done; next iter may restage
        }

        // ---- denominators + store ----
        float inv[4];
#pragma unroll
        for (int rr = 0; rr < 4; ++rr) {
            float d = pden[rr];
            d += __shfl_xor(d, 1, 16);
            d += __shfl_xor(d, 2, 16);
            d += __shfl_xor(d, 4, 16);
            d += __shfl_xor(d, 8, 16);
            inv[rr] = 1.0f / d;
        }
        float* outp = og + ((size_t)bh * N + i0 + band) * D;
#pragma unroll
        for (int nt = 0; nt < 4; ++nt)
#pragma unroll
            for (int rr = 0; rr < 4; ++rr)
                outp[(size_t)(quad * 4 + rr) * D + nt * 16 + x] = oacc[nt][rr] * inv[rr];
    }
}

extern "C" void kernel_launch(void* const* d_in, const int* in_sizes, int n_in,
                              void* d_out, int out_size, void* d_ws, size_t ws_size,
                              hipStream_t stream) {
    const float* q   = (const float*)d_in[0];
    const float* k   = (const float*)d_in[1];
    const float* v   = (const float*)d_in[2];
    const float* dn  = (const float*)d_in[3];
    const float* rpe = (const float*)d_in[4];
    float* out = (float*)d_out;
    char* ws = (char*)d_ws;

    ushort* kh = (ushort*)(ws + KH_OFF);
    ushort* kl = (ushort*)(ws + KL_OFF);
    ushort* vh = (ushort*)(ws + VH_OFF);
    ushort* vl = (ushort*)(ws + VL_OFF);
    ushort* rh = (ushort*)(ws + RH_OFF);
    ushort* rl = (ushort*)(ws + RL_OFF);

    prep_k  <<<dim3(N / 64, NBH), 256, 0, stream>>>(k, kh, kl);
    prep_v  <<<dim3(N / 64, NBH), 256, 0, stream>>>(v, dn, vh, vl);
    prep_rpe<<<dim3(32), 256, 0, stream>>>(rpe, rh, rl);
    fastmax_main<<<dim3(8, NBH), 256, 0, stream>>>(q, kh, kl, vh, vl, rh, rl, out);
}

// Round 7
// 171.680 us; speedup vs baseline: 1.2272x; 1.2254x over previous
//
#include <hip/hip_runtime.h>

// fastmax attention. b=4,h=16,n=1024,d=64 fp32. bf16x3 split precision.
// v7 = v4 main kernel EXACTLY (verified 80.1us: named-reg prefetch, QR 5
// w-tiles, Bst stride 18, batched gather phases, setprio) + all three prep
// kernels fused into ONE dispatch (grid (33,64), block-uniform branches).
// v5/v6 post-mortem: racc-carry's conditional MFMA mid-cluster broke the
// compiler's ds_read/MFMA interleave (+40%); fence placement was refuted as
// the cause (v6==v5). Main loop restored; control flow kept out of MFMA
// clusters. Launch count 4 -> 2 attacks the ~97us fixed non-main cost.

constexpr int N   = 1024;
constexpr int D   = 64;
constexpr int NBH = 64;
constexpr int LDT = 72;   // ushort stride of staged tiles

// ws layout (bytes)
constexpr size_t KH_OFF = 0;                                  // k_hi [bh][row][t]
constexpr size_t KL_OFF = KH_OFF + (size_t)NBH * N * D * 2;
constexpr size_t VH_OFF = KL_OFF + (size_t)NBH * N * D * 2;   // vt_hi [bh][dc][c]
constexpr size_t VL_OFF = VH_OFF + (size_t)NBH * N * D * 2;
constexpr size_t RH_OFF = VL_OFF + (size_t)NBH * N * D * 2;   // r_hi [rel 2048][t]
constexpr size_t RL_OFF = RH_OFF + (size_t)2048 * D * 2;

typedef short short8  __attribute__((ext_vector_type(8)));
typedef float float4v __attribute__((ext_vector_type(4)));

#define LDS_FENCE() asm volatile("s_waitcnt lgkmcnt(0)" ::: "memory")

__device__ __forceinline__ ushort f2bf(float x) {
    union { float f; unsigned u; } un; un.f = x;
    unsigned r = un.u + 0x7fffu + ((un.u >> 16) & 1u);   // RNE
    return (ushort)(r >> 16);
}
__device__ __forceinline__ float bf2f(ushort h) {
    union { unsigned u; float f; } un; un.u = ((unsigned)h) << 16;
    return un.f;
}
__device__ __forceinline__ void split2(float x, ushort& h, ushort& l) {
    h = f2bf(x);
    l = f2bf(x - bf2f(h));
}
__device__ __forceinline__ void pack16(const float* v, ushort* dh, ushort* dl) {
    ushort hh[16], ll[16];
#pragma unroll
    for (int j = 0; j < 16; ++j) split2(v[j], hh[j], ll[j]);
    uint4 a, b;
    a.x = hh[0] | (hh[1] << 16);  a.y = hh[2] | (hh[3] << 16);
    a.z = hh[4] | (hh[5] << 16);  a.w = hh[6] | (hh[7] << 16);
    b.x = hh[8] | (hh[9] << 16);  b.y = hh[10] | (hh[11] << 16);
    b.z = hh[12] | (hh[13] << 16); b.w = hh[14] | (hh[15] << 16);
    ((uint4*)dh)[0] = a; ((uint4*)dh)[1] = b;
    a.x = ll[0] | (ll[1] << 16);  a.y = ll[2] | (ll[3] << 16);
    a.z = ll[4] | (ll[5] << 16);  a.w = ll[6] | (ll[7] << 16);
    b.x = ll[8] | (ll[9] << 16);  b.y = ll[10] | (ll[11] << 16);
    b.z = ll[12] | (ll[13] << 16); b.w = ll[14] | (ll[15] << 16);
    ((uint4*)dl)[0] = a; ((uint4*)dl)[1] = b;
}

// ---- fused prep kernel: bx<16 -> k-split, bx<32 -> v-transpose, bx==32 -> rpe ----
__global__ __launch_bounds__(256) void prep_fused(
        const float* __restrict__ kg, const float* __restrict__ vg,
        const float* __restrict__ ng, const float* __restrict__ rg,
        ushort* __restrict__ kh, ushort* __restrict__ kl,
        ushort* __restrict__ vh, ushort* __restrict__ vl,
        ushort* __restrict__ rh, ushort* __restrict__ rl) {
    __shared__ ushort Th[64 * 72], Tl[64 * 72];
    const int bx = blockIdx.x;
    const int by = blockIdx.y;

    if (bx < 16) {
        // ---- prep_k: l2-normalize + bf16 hi/lo split ----
        const int bh = by;
        const int row = bx * 64 + (threadIdx.x >> 2);
        const int seg = threadIdx.x & 3;
        const float4* p = (const float4*)(kg + ((size_t)bh * N + row) * D + seg * 16);
        float4 f[4] = {p[0], p[1], p[2], p[3]};
        float ss = 0.f;
#pragma unroll
        for (int i = 0; i < 4; ++i)
            ss += f[i].x * f[i].x + f[i].y * f[i].y + f[i].z * f[i].z + f[i].w * f[i].w;
        ss += __shfl_xor(ss, 1, 4);
        ss += __shfl_xor(ss, 2, 4);
        const float rn = rsqrtf(ss);
        float v[16];
#pragma unroll
        for (int i = 0; i < 4; ++i) {
            v[4 * i + 0] = f[i].x * rn; v[4 * i + 1] = f[i].y * rn;
            v[4 * i + 2] = f[i].z * rn; v[4 * i + 3] = f[i].w * rn;
        }
        const size_t o = ((size_t)bh * N + row) * D + seg * 16;
        pack16(v, kh + o, kl + o);
    } else if (bx < 32) {
        // ---- prep_v: v' = v + 0.1*noise, transpose to dc-major, split ----
        const int bh = by, c0 = (bx - 16) * 64;
        const int cl = threadIdx.x >> 2, seg = threadIdx.x & 3;
        {
            const float4* pv = (const float4*)(vg + ((size_t)bh * N + c0 + cl) * D + seg * 16);
            const float4* pn = (const float4*)(ng + ((size_t)bh * N + c0 + cl) * D + seg * 16);
#pragma unroll
            for (int i = 0; i < 4; ++i) {
                float4 fv = pv[i], fn = pn[i];
                float va[4] = {fv.x + 0.1f * fn.x, fv.y + 0.1f * fn.y,
                               fv.z + 0.1f * fn.z, fv.w + 0.1f * fn.w};
#pragma unroll
                for (int j = 0; j < 4; ++j) {
                    ushort hh, ll;
                    split2(va[j], hh, ll);
                    const int dc = seg * 16 + i * 4 + j;
                    Th[dc * 72 + cl] = hh;
                    Tl[dc * 72 + cl] = ll;
                }
            }
        }
        __syncthreads();
        {
            const int dc = threadIdx.x >> 2;
            const size_t o = ((size_t)bh * D + dc) * N + c0 + seg * 16;
            uint4* sh = (uint4*)&Th[dc * 72 + seg * 16];
            uint4* sl = (uint4*)&Tl[dc * 72 + seg * 16];
            ((uint4*)(vh + o))[0] = sh[0]; ((uint4*)(vh + o))[1] = sh[1];
            ((uint4*)(vl + o))[0] = sl[0]; ((uint4*)(vl + o))[1] = sl[1];
        }
    } else {
        // ---- prep_rpe: bf16 hi/lo split of rpe rows (by = block 0..31) ----
        if (by >= 32) return;
        const int row = by * 64 + (threadIdx.x >> 2);
        if (row >= 2 * N - 1) return;
        const int seg = threadIdx.x & 3;
        const float4* p = (const float4*)(rg + (size_t)row * D + seg * 16);
        float4 f[4] = {p[0], p[1], p[2], p[3]};
        float v[16];
#pragma unroll
        for (int i = 0; i < 4; ++i) {
            v[4 * i + 0] = f[i].x; v[4 * i + 1] = f[i].y;
            v[4 * i + 2] = f[i].z; v[4 * i + 3] = f[i].w;
        }
        const size_t o = (size_t)row * D + seg * 16;
        pack16(v, rh + o, rl + o);
    }
}

// ---- main (byte-identical to v4, verified 80.1us) ----
__device__ __forceinline__ float4v mfma6(short8 ah0, short8 ah1, short8 al0, short8 al1,
                                         const ushort* ph, const ushort* pl, float4v c) {
    short8 bh0 = *(const short8*)ph;
    short8 bh1 = *(const short8*)(ph + 32);
    short8 bl0 = *(const short8*)pl;
    short8 bl1 = *(const short8*)(pl + 32);
    c = __builtin_amdgcn_mfma_f32_16x16x32_bf16(ah0, bh0, c, 0, 0, 0);
    c = __builtin_amdgcn_mfma_f32_16x16x32_bf16(ah1, bh1, c, 0, 0, 0);
    c = __builtin_amdgcn_mfma_f32_16x16x32_bf16(ah0, bl0, c, 0, 0, 0);
    c = __builtin_amdgcn_mfma_f32_16x16x32_bf16(ah1, bl1, c, 0, 0, 0);
    c = __builtin_amdgcn_mfma_f32_16x16x32_bf16(al0, bh0, c, 0, 0, 0);
    c = __builtin_amdgcn_mfma_f32_16x16x32_bf16(al1, bh1, c, 0, 0, 0);
    return c;
}

// Prefetch next K/V/R tile into 16 NAMED uint4 (64 VGPRs). No arrays, no
// lambdas -> nothing address-taken -> guaranteed register allocation.
#define PREFETCH(i0loc, jtv) do {                                         \
    const int j0_   = (jtv) * 64;                                         \
    const int rel0_ = (i0loc) - j0_ + N - 64;                             \
    const ushort* gKh_ = khb + (size_t)j0_ * D;                           \
    const ushort* gKl_ = klb + (size_t)j0_ * D;                           \
    const ushort* gVh_ = vhb + j0_;                                       \
    const ushort* gVl_ = vlb + j0_;                                       \
    const ushort* gRh_ = rh + (size_t)rel0_ * D;                          \
    const ushort* gRl_ = rl + (size_t)rel0_ * D;                          \
    pKh0 = *(const uint4*)&gKh_[r0 * D + c8];                             \
    pKh1 = *(const uint4*)&gKh_[(r0 + 32) * D + c8];                      \
    pKl0 = *(const uint4*)&gKl_[r0 * D + c8];                             \
    pKl1 = *(const uint4*)&gKl_[(r0 + 32) * D + c8];                      \
    pVh0 = *(const uint4*)&gVh_[(size_t)r0 * N + c8];                     \
    pVh1 = *(const uint4*)&gVh_[(size_t)(r0 + 32) * N + c8];              \
    pVl0 = *(const uint4*)&gVl_[(size_t)r0 * N + c8];                     \
    pVl1 = *(const uint4*)&gVl_[(size_t)(r0 + 32) * N + c8];              \
    pRh0 = *(const uint4*)&gRh_[r0 * D + c8];                             \
    pRh1 = *(const uint4*)&gRh_[(r0 + 32) * D + c8];                      \
    pRh2 = *(const uint4*)&gRh_[(r0 + 64) * D + c8];                      \
    pRh3 = *(const uint4*)&gRh_[(r0 + 96) * D + c8];                      \
    pRl0 = *(const uint4*)&gRl_[r0 * D + c8];                             \
    pRl1 = *(const uint4*)&gRl_[(r0 + 32) * D + c8];                      \
    pRl2 = *(const uint4*)&gRl_[(r0 + 64) * D + c8];                      \
    pRl3 = *(const uint4*)&gRl_[(r0 + 96) * D + c8];                      \
} while (0)

#define STAGE_WRITE() do {                                                \
    *(uint4*)&Kh[r0 * LDT + c8]        = pKh0;                            \
    *(uint4*)&Kh[(r0 + 32) * LDT + c8] = pKh1;                            \
    *(uint4*)&Kl[r0 * LDT + c8]        = pKl0;                            \
    *(uint4*)&Kl[(r0 + 32) * LDT + c8] = pKl1;                            \
    *(uint4*)&Vh[r0 * LDT + c8]        = pVh0;                            \
    *(uint4*)&Vh[(r0 + 32) * LDT + c8] = pVh1;                            \
    *(uint4*)&Vl[r0 * LDT + c8]        = pVl0;                            \
    *(uint4*)&Vl[(r0 + 32) * LDT + c8] = pVl1;                            \
    *(uint4*)&Rh[r0 * LDT + c8]        = pRh0;                            \
    *(uint4*)&Rh[(r0 + 32) * LDT + c8] = pRh1;                            \
    *(uint4*)&Rh[(r0 + 64) * LDT + c8] = pRh2;                            \
    *(uint4*)&Rh[(r0 + 96) * LDT + c8] = pRh3;                            \
    *(uint4*)&Rl[r0 * LDT + c8]        = pRl0;                            \
    *(uint4*)&Rl[(r0 + 32) * LDT + c8] = pRl1;                            \
    *(uint4*)&Rl[(r0 + 64) * LDT + c8] = pRl2;                            \
    *(uint4*)&Rl[(r0 + 96) * LDT + c8] = pRl3;                            \
} while (0)

__global__ __launch_bounds__(256, 2)
void fastmax_main(const float* __restrict__ qg,
                  const ushort* __restrict__ kh, const ushort* __restrict__ kl,
                  const ushort* __restrict__ vh, const ushort* __restrict__ vl,
                  const ushort* __restrict__ rh, const ushort* __restrict__ rl,
                  float* __restrict__ og) {
    __shared__ __align__(16) char smem[73728];
    ushort* Kh = (ushort*)smem;           // [64][LDT]
    ushort* Kl = Kh + 64 * LDT;
    ushort* Rh = Kl + 64 * LDT;           // [128][LDT]
    ushort* Rl = Rh + 128 * LDT;
    ushort* Vh = Rl + 128 * LDT;          // [64][LDT] (dc-major)
    ushort* Vl = Vh + 64 * LDT;

    const int tid  = threadIdx.x;
    const int lane = tid & 63;
    const int wv   = tid >> 6;
    const int bh   = blockIdx.y;
    const int x    = lane & 15;
    const int quad = lane >> 4;
    const int band = wv * 16;
    const int r0   = tid >> 3;            // staging row for this thread
    const int c8   = (tid & 7) * 8;       // staging col (ushorts)

    // per-wave scratch overlays Kh/Kl/start-of-Rh (dead between barriers B..D)
    float*  Bst = (float*)(smem + wv * 5760);   // [80][18] f32
    ushort* Sh  = (ushort*)(smem + wv * 5760);  // [16][LDT] bf16
    ushort* Sl  = Sh + 16 * LDT;

    const ushort* khb = kh + (size_t)bh * N * D;
    const ushort* klb = kl + (size_t)bh * N * D;
    const ushort* vhb = vh + (size_t)bh * D * N;
    const ushort* vlb = vl + (size_t)bh * D * N;

    // named prefetch registers (16 uint4 = 64 VGPRs)
    uint4 pKh0, pKh1, pKl0, pKl1, pVh0, pVh1, pVl0, pVl1;
    uint4 pRh0, pRh1, pRh2, pRh3, pRl0, pRl1, pRl2, pRl3;

    for (int half = 0; half < 2; ++half) {
        const int bix = half == 0 ? (int)blockIdx.x + 8 : 7 - (int)blockIdx.x;
        const int i0  = bix * 64;

        // ---- this wave's 16 q rows -> normalized bf16x2 A-frags ----
        const float* qrow = qg + ((size_t)bh * N + i0 + band + x) * D;
        float qf[16];
        *(float4*)&qf[0]  = *(const float4*)(qrow + quad * 8);
        *(float4*)&qf[4]  = *(const float4*)(qrow + quad * 8 + 4);
        *(float4*)&qf[8]  = *(const float4*)(qrow + 32 + quad * 8);
        *(float4*)&qf[12] = *(const float4*)(qrow + 32 + quad * 8 + 4);
        float ss = 0.f;
#pragma unroll
        for (int j = 0; j < 16; ++j) ss += qf[j] * qf[j];
        ss += __shfl_xor(ss, 16);
        ss += __shfl_xor(ss, 32);
        const float rn = rsqrtf(ss);
        short8 qh0, ql0, qh1, ql1;
#pragma unroll
        for (int j = 0; j < 8; ++j) {
            ushort h, l;
            split2(qf[j] * rn, h, l);      qh0[j] = (short)h; ql0[j] = (short)l;
            split2(qf[8 + j] * rn, h, l);  qh1[j] = (short)h; ql1[j] = (short)l;
        }

        float4v oacc[4];
#pragma unroll
        for (int i = 0; i < 4; ++i) oacc[i] = (float4v){0.f, 0.f, 0.f, 0.f};
        float pden[4] = {0.f, 0.f, 0.f, 0.f};

        if (half == 0) PREFETCH(i0, 0);   // cold start; all later tiles overlap

        for (int jt = 0; jt <= bix; ++jt) {
            // ---- dump prefetched tile to LDS (prev iter's reads done at D) ----
            STAGE_WRITE();
            __syncthreads();   // A: staging visible

            // ---- issue next prefetch (drains under QK/QR/PV MFMAs) ----
            if (jt < bix) {
                PREFETCH(i0, jt + 1);
            } else if (half == 0) {
                const int i0n = (7 - (int)blockIdx.x) * 64;
                PREFETCH(i0n, 0);
            }

            // ---- QK^T ----
            __builtin_amdgcn_s_setprio(1);
            float4v sacc[4];
#pragma unroll
            for (int nt = 0; nt < 4; ++nt) {
                const int off = (nt * 16 + x) * LDT + quad * 8;
                float4v c = (float4v){0.f, 0.f, 0.f, 0.f};
                sacc[nt] = mfma6(qh0, qh1, ql0, ql1, &Kh[off], &Kl[off], c);
            }
            // ---- QR: 5 w-tiles this wave gathers from (w in [band, band+80)) ----
            float4v racc[5];
#pragma unroll
            for (int t = 0; t < 5; ++t) {
                const int off = (band + t * 16 + x) * LDT + quad * 8;
                float4v c = (float4v){0.f, 0.f, 0.f, 0.f};
                racc[t] = mfma6(qh0, qh1, ql0, ql1, &Rh[off], &Rl[off], c);
            }
            __builtin_amdgcn_s_setprio(0);
            __syncthreads();   // B: K/R LDS reads done; scratch region free

            // ---- intra-wave Bst transpose ----
#pragma unroll
            for (int t = 0; t < 5; ++t) {
                float* p = &Bst[(t * 16 + x) * 18 + quad * 4];
                float2 a; a.x = racc[t][0]; a.y = racc[t][1];
                float2 b; b.x = racc[t][2]; b.y = racc[t][3];
                *(float2*)p = a;
                *(float2*)(p + 2) = b;
            }
            LDS_FENCE();

            // ---- gather bias, assemble S, denom ----
            const bool diag = (jt == bix);
            float s[4][4];
#pragma unroll
            for (int nt = 0; nt < 4; ++nt) {
#pragma unroll
                for (int rr = 0; rr < 4; ++rr) {
                    const int rt = band + quad * 4 + rr;
                    const int ct = nt * 16 + x;
                    const int wl = rt - ct + 63 - band;     // [0, 78]
                    float val = sacc[nt][rr] + Bst[wl * 18 + quad * 4 + rr] + 1.0f;
                    if (diag && ct > rt) val = 0.f;
                    pden[rr] += val;
                    s[nt][rr] = val;
                }
            }
            LDS_FENCE();

            // ---- intra-wave S hi/lo store + A-frag reload ----
#pragma unroll
            for (int nt = 0; nt < 4; ++nt)
#pragma unroll
                for (int rr = 0; rr < 4; ++rr) {
                    ushort hh, ll;
                    split2(s[nt][rr], hh, ll);
                    Sh[(quad * 4 + rr) * LDT + nt * 16 + x] = hh;
                    Sl[(quad * 4 + rr) * LDT + nt * 16 + x] = ll;
                }
            LDS_FENCE();
            const short8 sh0 = *(const short8*)&Sh[x * LDT + quad * 8];
            const short8 sh1 = *(const short8*)&Sh[x * LDT + 32 + quad * 8];
            const short8 sl0 = *(const short8*)&Sl[x * LDT + quad * 8];
            const short8 sl1 = *(const short8*)&Sl[x * LDT + 32 + quad * 8];

            // ---- O += S @ V' ----
            __builtin_amdgcn_s_setprio(1);
#pragma unroll
            for (int nt = 0; nt < 4; ++nt) {
                const int off = (nt * 16 + x) * LDT + quad * 8;
                oacc[nt] = mfma6(sh0, sh1, sl0, sl1, &Vh[off], &Vl[off], oacc[nt]);
            }
            __builtin_amdgcn_s_setprio(0);
            __syncthreads();   // D: all reads done; next iter may restage
        }

        // ---- denominators + store ----
        float inv[4];
#pragma unroll
        for (int rr = 0; rr < 4; ++rr) {
            float d = pden[rr];
            d += __shfl_xor(d, 1, 16);
            d += __shfl_xor(d, 2, 16);
            d += __shfl_xor(d, 4, 16);
            d += __shfl_xor(d, 8, 16);
            inv[rr] = 1.0f / d;
        }
        float* outp = og + ((size_t)bh * N + i0 + band) * D;
#pragma unroll
        for (int nt = 0; nt < 4; ++nt)
#pragma unroll
            for (int rr = 0; rr < 4; ++rr)
                outp[(size_t)(quad * 4 + rr) * D + nt * 16 + x] = oacc[nt][rr] * inv[rr];
    }
}

extern "C" void kernel_launch(void* const* d_in, const int* in_sizes, int n_in,
                              void* d_out, int out_size, void* d_ws, size_t ws_size,
                              hipStream_t stream) {
    const float* q   = (const float*)d_in[0];
    const float* k   = (const float*)d_in[1];
    const float* v   = (const float*)d_in[2];
    const float* dn  = (const float*)d_in[3];
    const float* rpe = (const float*)d_in[4];
    float* out = (float*)d_out;
    char* ws = (char*)d_ws;

    ushort* kh = (ushort*)(ws + KH_OFF);
    ushort* kl = (ushort*)(ws + KL_OFF);
    ushort* vh = (ushort*)(ws + VH_OFF);
    ushort* vl = (ushort*)(ws + VL_OFF);
    ushort* rh = (ushort*)(ws + RH_OFF);
    ushort* rl = (ushort*)(ws + RL_OFF);

    prep_fused<<<dim3(33, NBH), 256, 0, stream>>>(k, v, dn, rpe, kh, kl, vh, vl, rh, rl);
    fastmax_main<<<dim3(8, NBH), 256, 0, stream>>>(q, kh, kl, vh, vl, rh, rl, out);
}